// Round 4
// baseline (106.495 us; speedup 1.0000x reference)
//
#include <hip/hip_runtime.h>
#include <math.h>

// B=32, HW=4096 (64x64), C=256, G=32, CG=8 -> 1024 samples of (8,64,64).
// One workgroup per sample; gx resident in LDS as packed bf16 pairs.
// 1024 threads (16 waves) x 2 blocks/CU = 32 waves/CU (full occupancy).
// LDS ~78.6 KB/block.

#define NBLK 1024
#define NTHR 1024
#define CSTR 2052   // u32 per channel (4104 bf16 = 4096 px + pad)

typedef unsigned int uint;

__device__ __forceinline__ uint pk2(float a, float b) {   // 2x f32 -> packed bf16 (RNE)
    uint ua = __builtin_bit_cast(uint, a);
    uint ub = __builtin_bit_cast(uint, b);
    ua = (ua + 0x7FFFu + ((ua >> 16) & 1u)) >> 16;
    ub = (ub + 0x7FFFu + ((ub >> 16) & 1u)) >> 16;
    return ua | (ub << 16);
}
__device__ __forceinline__ float blo(uint u) { return __builtin_bit_cast(float, u << 16); }
__device__ __forceinline__ float bhi(uint u) { return __builtin_bit_cast(float, u & 0xFFFF0000u); }
__device__ __forceinline__ float sigm(float v) { return 1.0f / (1.0f + __expf(-v)); }

__global__ __launch_bounds__(1024, 8) void fused_ema_kernel(
    const float* __restrict__ x,     // (32, 4096, 256)
    const float* __restrict__ w1,    // (8,8)
    const float* __restrict__ b1,    // (8)
    const float* __restrict__ w3,    // (8,8,3,3)
    const float* __restrict__ b3,    // (8)
    const float* __restrict__ gn_w,  // (8)
    const float* __restrict__ gn_b,  // (8)
    float* __restrict__ out)         // (32, 4096, 256)
{
    __shared__ __align__(16) uint  gxp[8 * CSTR];   // 65,664 B: bf16-pair gx [i][y][x]
    __shared__ __align__(16) float sg[8 * 128];     // 4 KB: [:64]=sh(y), [64:]=sw(x)
    __shared__ __align__(16) float uni[1024];       // 4 KB: Rs [0:512) | Cs [512:1024)
    __shared__ __align__(16) float csp1[512];       // 2 KB: col-sum partial (y-half 1)
    __shared__ __align__(16) float t1s[512];        // 2 KB: x21*Ai*sh[y]
    __shared__ float weff[72];                      // sum_o x11[o]*w3[o,i,:,:]
    __shared__ float Ti[8], m2s[8], Ai[8], Ci[8], x11s[8], x21s[8];
    __shared__ float sPart[16], s2Part[16];
    __shared__ float wconst_s;

    const int t = threadIdx.x;
    // quad (same b, 4 consecutive g sharing each 128B line) -> same XCD, close slots
    const int bi = blockIdx.x;
    const int n = ((bi & 7) * 32 + ((bi >> 3) >> 2)) * 4 + ((bi >> 3) & 3);
    const int b = n >> 5;
    const int g = n & 31;

    // ---------------- Phase 1: load x -> LDS (bf16 pairs) -------------------
    {
        const float4* x4 = reinterpret_cast<const float4*>(x) + (size_t)b * 4096 * 64 + g * 2;
#pragma unroll
        for (int k = 0; k < 4; ++k) {
            int idx = k * 1024 + t;       // 0..4095
            int q = idx >> 1;             // pixel pair 0..2047
            int half = idx & 1;
            float4 v0 = x4[(size_t)q * 128 + half];        // px 2q
            float4 v1 = x4[(size_t)q * 128 + 64 + half];   // px 2q+1
            int ch = half * 4;
            gxp[(ch + 0) * CSTR + q] = pk2(v0.x, v1.x);
            gxp[(ch + 1) * CSTR + q] = pk2(v0.y, v1.y);
            gxp[(ch + 2) * CSTR + q] = pk2(v0.z, v1.z);
            gxp[(ch + 3) * CSTR + q] = pk2(v0.w, v1.w);
        }
    }
    __syncthreads();

    float* Rs = uni;
    float* Cs = uni + 512;

    // ---------------- Phase 2: Rs / Cs partials / Ti ------------------------
    {
        const int i = t >> 7, l = t & 127;
        const int ys2 = l >> 4, xb2 = l & 15;   // 8 y-slots x 16 x-chunks (4 px)
        float c0 = 0.f, c1 = 0.f, c2 = 0.f, c3 = 0.f;
        float rowv[8];
#pragma unroll
        for (int r = 0; r < 8; ++r) {
            const uint2 d = *reinterpret_cast<const uint2*>(
                &gxp[i * CSTR + (ys2 * 8 + r) * 32 + xb2 * 2]);
            float f0 = blo(d.x), f1 = bhi(d.x), f2 = blo(d.y), f3 = bhi(d.y);
            rowv[r] = (f0 + f1) + (f2 + f3);
            c0 += f0; c1 += f1; c2 += f2; c3 += f3;
        }
#pragma unroll
        for (int r = 0; r < 8; ++r) {
            float v = rowv[r];
            v += __shfl_xor(v, 1); v += __shfl_xor(v, 2);
            v += __shfl_xor(v, 4); v += __shfl_xor(v, 8);
            if (xb2 == 0) Rs[i * 64 + ys2 * 8 + r] = v;
        }
        // combine the 4 ys2-groups within each wave (lanes stride 16)
        c0 += __shfl_xor(c0, 16); c0 += __shfl_xor(c0, 32);
        c1 += __shfl_xor(c1, 16); c1 += __shfl_xor(c1, 32);
        c2 += __shfl_xor(c2, 16); c2 += __shfl_xor(c2, 32);
        c3 += __shfl_xor(c3, 16); c3 += __shfl_xor(c3, 32);
        if ((l & 63) < 16) {
            float* dst = (l < 64) ? &Cs[i * 64 + xb2 * 4] : &csp1[i * 64 + xb2 * 4];
            *reinterpret_cast<float4*>(dst) = make_float4(c0, c1, c2, c3);
        }
    }
    __syncthreads();
    if (t < 512) {
        const int i = t >> 6, j = t & 63;
        float c = Cs[t] + csp1[t];
        Cs[t] = c;
        float s = c;
#pragma unroll
        for (int off = 32; off; off >>= 1) s += __shfl_xor(s, off);
        if (j == 0) Ti[i] = s;
    }
    __syncthreads();

    // ---------------- Phase 3: gate matmul (8x8) + sigmoid ------------------
    {
        const int o = t >> 7, p = t & 127;   // p<64: y-gate, p>=64: x-gate
        float val = b1[o];
#pragma unroll
        for (int i = 0; i < 8; ++i) {
            float cv = (p < 64) ? Rs[i * 64 + p] : Cs[i * 64 + (p - 64)];
            val += w1[o * 8 + i] * (cv * (1.0f / 64.0f));
        }
        sg[o * 128 + p] = sigm(val);
    }
    __syncthreads();

    // ---------------- Phase 4: instance-norm stats --------------------------
    {
        const int i = t >> 7, l = t & 127;
        const int ys2 = l >> 4, xb2 = l & 15;
        const float4 sa = *reinterpret_cast<const float4*>(&sg[i * 128 + 64 + xb2 * 4]);
        float s = 0.f, s2 = 0.f;
#pragma unroll
        for (int r = 0; r < 8; ++r) {
            const float shv = sg[i * 128 + ys2 * 8 + r];
            const uint2 d = *reinterpret_cast<const uint2*>(
                &gxp[i * CSTR + (ys2 * 8 + r) * 32 + xb2 * 2]);
            float g0 = blo(d.x) * shv * sa.x; s += g0; s2 += g0 * g0;
            float g1 = bhi(d.x) * shv * sa.y; s += g1; s2 += g1 * g1;
            float g2 = blo(d.y) * shv * sa.z; s += g2; s2 += g2 * g2;
            float g3 = bhi(d.y) * shv * sa.w; s += g3; s2 += g3 * g3;
        }
#pragma unroll
        for (int off = 32; off; off >>= 1) {
            s += __shfl_xor(s, off);
            s2 += __shfl_xor(s2, off);
        }
        if ((t & 63) == 0) { sPart[t >> 6] = s; s2Part[t >> 6] = s2; }
    }
    __syncthreads();

    // ---- Phase 5a/5b (wave 0 only): finalize stats, conv means, softmaxes --
    if (t < 8) {
        float s  = sPart[2 * t] + sPart[2 * t + 1];
        float s2 = s2Part[2 * t] + s2Part[2 * t + 1];
        float mu = s * (1.0f / 4096.0f);
        float var = s2 * (1.0f / 4096.0f) - mu * mu;
        float a = rsqrtf(var + 1e-5f) * gn_w[t];
        Ai[t] = a;
        Ci[t] = gn_b[t] - mu * a;
    }
    if (t < 64) {
        const int o = t >> 3, i = t & 7;
        const float T = Ti[i];
        float part = 0.f;
#pragma unroll
        for (int ky = 0; ky < 3; ++ky) {
            int dy = ky - 1;
#pragma unroll
            for (int kx = 0; kx < 3; ++kx) {
                int dx = kx - 1;
                float S = T;
                int er = (dy < 0) ? 63 : 0;
                int ec = (dx < 0) ? 63 : 0;
                if (dy != 0) S -= Rs[i * 64 + er];
                if (dx != 0) S -= Cs[i * 64 + ec];
                if (dy != 0 && dx != 0) {
                    uint u = gxp[i * CSTR + er * 32 + (ec >> 1)];
                    S += (ec & 1) ? bhi(u) : blo(u);
                }
                part += w3[((o * 8 + i) * 3 + ky) * 3 + kx] * S;
            }
        }
        part += __shfl_xor(part, 1); part += __shfl_xor(part, 2); part += __shfl_xor(part, 4);
        if (i == 0) m2s[o] = part * (1.0f / 4096.0f) + b3[o];
    }
    if (t < 8) {
        float mx = m2s[0];
#pragma unroll
        for (int o = 1; o < 8; ++o) mx = fmaxf(mx, m2s[o]);
        float sum = 0.f;
#pragma unroll
        for (int o = 0; o < 8; ++o) sum += __expf(m2s[o] - mx);
        x21s[t] = __expf(m2s[t] - mx) / sum;
        // x1 per-channel spatial mean == gn_b exactly (normalized field)
        float mx1 = gn_b[0];
#pragma unroll
        for (int o = 1; o < 8; ++o) mx1 = fmaxf(mx1, gn_b[o]);
        float sum1 = 0.f;
#pragma unroll
        for (int o = 0; o < 8; ++o) sum1 += __expf(gn_b[o] - mx1);
        x11s[t] = __expf(gn_b[t] - mx1) / sum1;
    }
    __syncthreads();

    // ---- Phase 5c: collapsed filter, t1, constants -------------------------
    if (t < 72) {
        const int i = t / 9, k = t % 9;
        float acc = 0.f;
#pragma unroll
        for (int o = 0; o < 8; ++o) acc += x11s[o] * w3[(o * 8 + i) * 9 + k];
        weff[i * 9 + k] = acc;
    }
    if (t < 512) {
        const int i = t >> 6, y = t & 63;
        t1s[i * 64 + y] = x21s[i] * Ai[i] * sg[i * 128 + y];
    }
    if (t == 0) {
        float wc = 0.f;
#pragma unroll
        for (int o = 0; o < 8; ++o) wc += x11s[o] * b3[o] + x21s[o] * Ci[o];
        wconst_s = wc;
    }
    __syncthreads();

    // ---- Phase 6: per-pixel weight, sigmoid, output (fused) ----------------
    {
        const int y = t >> 4, xq = t & 15;       // 4 consecutive px per thread
        const bool xl = (xq == 0), xr = (xq == 15);
        float ws0 = wconst_s, ws1 = wconst_s, ws2 = wconst_s, ws3 = wconst_s;
        uint2 gg[8];
#pragma unroll
        for (int i = 0; i < 8; ++i) {
            const float t1v = t1s[i * 64 + y];
            const float4 sa = *reinterpret_cast<const float4*>(&sg[i * 128 + 64 + xq * 4]);
#pragma unroll
            for (int dy = -1; dy <= 1; ++dy) {
                const int yy = y + dy;
                if (yy < 0 || yy > 63) continue;     // only first/last y-group diverges
                const uint2 d = *reinterpret_cast<const uint2*>(
                    &gxp[i * CSTR + yy * 32 + xq * 2]);
                float f0 = blo(d.x), f1 = bhi(d.x), f2 = blo(d.y), f3 = bhi(d.y);
                float vm = __shfl_up(f3, 1);         // lane-1's f3 (same yy row)
                float vp = __shfl_down(f0, 1);       // lane+1's f0
                vm = xl ? 0.f : vm;
                vp = xr ? 0.f : vp;
                const float wl = weff[i * 9 + (dy + 1) * 3 + 0];
                const float wc = weff[i * 9 + (dy + 1) * 3 + 1];
                const float wr = weff[i * 9 + (dy + 1) * 3 + 2];
                ws0 += wl * vm + wc * f0 + wr * f1;
                ws1 += wl * f0 + wc * f1 + wr * f2;
                ws2 += wl * f1 + wc * f2 + wr * f3;
                ws3 += wl * f2 + wc * f3 + wr * vp;
                if (dy == 0) {
                    gg[i] = d;
                    ws0 += t1v * sa.x * f0;  ws1 += t1v * sa.y * f1;
                    ws2 += t1v * sa.z * f2;  ws3 += t1v * sa.w * f3;
                }
            }
        }
        const float s0 = sigm(ws0), s1 = sigm(ws1), s2 = sigm(ws2), s3 = sigm(ws3);
        float4* out4 = reinterpret_cast<float4*>(out) + (size_t)b * 4096 * 64 + g * 2;
        const size_t pb = (size_t)(y * 64 + xq * 4) * 64;
        float4 lo, hi;
        lo.x = blo(gg[0].x) * s0; lo.y = blo(gg[1].x) * s0; lo.z = blo(gg[2].x) * s0; lo.w = blo(gg[3].x) * s0;
        hi.x = blo(gg[4].x) * s0; hi.y = blo(gg[5].x) * s0; hi.z = blo(gg[6].x) * s0; hi.w = blo(gg[7].x) * s0;
        out4[pb + 0] = lo; out4[pb + 1] = hi;
        lo.x = bhi(gg[0].x) * s1; lo.y = bhi(gg[1].x) * s1; lo.z = bhi(gg[2].x) * s1; lo.w = bhi(gg[3].x) * s1;
        hi.x = bhi(gg[4].x) * s1; hi.y = bhi(gg[5].x) * s1; hi.z = bhi(gg[6].x) * s1; hi.w = bhi(gg[7].x) * s1;
        out4[pb + 64] = lo; out4[pb + 65] = hi;
        lo.x = blo(gg[0].y) * s2; lo.y = blo(gg[1].y) * s2; lo.z = blo(gg[2].y) * s2; lo.w = blo(gg[3].y) * s2;
        hi.x = blo(gg[4].y) * s2; hi.y = blo(gg[5].y) * s2; hi.z = blo(gg[6].y) * s2; hi.w = blo(gg[7].y) * s2;
        out4[pb + 128] = lo; out4[pb + 129] = hi;
        lo.x = bhi(gg[0].y) * s3; lo.y = bhi(gg[1].y) * s3; lo.z = bhi(gg[2].y) * s3; lo.w = bhi(gg[3].y) * s3;
        hi.x = bhi(gg[4].y) * s3; hi.y = bhi(gg[5].y) * s3; hi.z = bhi(gg[6].y) * s3; hi.w = bhi(gg[7].y) * s3;
        out4[pb + 192] = lo; out4[pb + 193] = hi;
    }
}

extern "C" void kernel_launch(void* const* d_in, const int* in_sizes, int n_in,
                              void* d_out, int out_size, void* d_ws, size_t ws_size,
                              hipStream_t stream) {
    const float* x    = (const float*)d_in[0];
    const float* w1   = (const float*)d_in[1];
    const float* b1   = (const float*)d_in[2];
    const float* w3   = (const float*)d_in[3];
    const float* b3   = (const float*)d_in[4];
    const float* gn_w = (const float*)d_in[5];
    const float* gn_b = (const float*)d_in[6];
    float* out = (float*)d_out;

    hipLaunchKernelGGL(fused_ema_kernel, dim3(NBLK), dim3(NTHR), 0, stream,
                       x, w1, b1, w3, b3, gn_w, gn_b, out);
}

// Round 5
// 82.938 us; speedup vs baseline: 1.2840x; 1.2840x over previous
//
#include <hip/hip_runtime.h>
#include <math.h>

// B=32, HW=4096 (64x64), C=256, G=32, CG=8 -> 1024 samples of (8,64,64).
// One workgroup per sample; gx resident in LDS as packed bf16 pairs.
// 512 threads (8 waves) x 2 blocks/CU. LDS ~76.5 KB/block.

#define NBLK 1024
#define NTHR 512
#define CSTR 2052   // u32 per channel (4104 bf16 = 4096 px + pad)

typedef unsigned int uint;

__device__ __forceinline__ uint pk2(float a, float b) {   // 2x f32 -> packed bf16 (RNE)
    uint ua = __builtin_bit_cast(uint, a);
    uint ub = __builtin_bit_cast(uint, b);
    ua = (ua + 0x7FFFu + ((ua >> 16) & 1u)) >> 16;
    ub = (ub + 0x7FFFu + ((ub >> 16) & 1u)) >> 16;
    return ua | (ub << 16);
}
__device__ __forceinline__ float blo(uint u) { return __builtin_bit_cast(float, u << 16); }
__device__ __forceinline__ float bhi(uint u) { return __builtin_bit_cast(float, u & 0xFFFF0000u); }
__device__ __forceinline__ float sigm(float v) { return 1.0f / (1.0f + __expf(-v)); }

__global__ __launch_bounds__(512, 4) void fused_ema_kernel(
    const float* __restrict__ x,     // (32, 4096, 256)
    const float* __restrict__ w1,    // (8,8)
    const float* __restrict__ b1,    // (8)
    const float* __restrict__ w3,    // (8,8,3,3)
    const float* __restrict__ b3,    // (8)
    const float* __restrict__ gn_w,  // (8)
    const float* __restrict__ gn_b,  // (8)
    float* __restrict__ out)         // (32, 4096, 256)
{
    __shared__ __align__(16) uint  gxp[8 * CSTR];   // 65,664 B: bf16-pair gx [i][y][x]
    __shared__ __align__(16) float sg[8 * 128];     // 4 KB: [:64]=sh(y), [64:]=sw(x)
    __shared__ __align__(16) float uni[1024];       // 4 KB: Rs [0:512) | Cs [512:1024)
    __shared__ __align__(16) float t1s[512];        // 2 KB: x21*Ai*sh[y]
    __shared__ __align__(16) float weff[96];        // [8][12] padded collapsed filter
    __shared__ float Ti[8], m2s[8], Ai[8], Ci[8], x11s[8], x21s[8];
    __shared__ float wconst_s;

    const int t = threadIdx.x;
    // quad (same b, 4 consecutive g sharing each 128B line) -> same XCD, close slots
    const int bi = blockIdx.x;
    const int n = ((bi & 7) * 32 + ((bi >> 3) >> 2)) * 4 + ((bi >> 3) & 3);
    const int b = n >> 5;
    const int g = n & 31;

    // ---------------- Phase 1: load x -> LDS (bf16 pairs) -------------------
    {
        const float4* x4 = reinterpret_cast<const float4*>(x) + (size_t)b * 4096 * 64 + g * 2;
#pragma unroll
        for (int k = 0; k < 8; ++k) {
            int idx = k * 512 + t;        // 0..4095
            int q = idx >> 1;             // pixel pair 0..2047
            int half = idx & 1;
            float4 v0 = x4[(size_t)q * 128 + half];        // px 2q
            float4 v1 = x4[(size_t)q * 128 + 64 + half];   // px 2q+1
            int ch = half * 4;
            gxp[(ch + 0) * CSTR + q] = pk2(v0.x, v1.x);
            gxp[(ch + 1) * CSTR + q] = pk2(v0.y, v1.y);
            gxp[(ch + 2) * CSTR + q] = pk2(v0.z, v1.z);
            gxp[(ch + 3) * CSTR + q] = pk2(v0.w, v1.w);
        }
    }
    __syncthreads();

    float* Rs = uni;          // [8][64] row sums (over x)
    float* Cs = uni + 512;    // [8][64] col sums (over y)

    // ---------------- Phase 2: Rs/Cs/Ti via b128 + shfl ---------------------
    {
        const int i = t >> 6, l = t & 63, ys = l >> 3, xb = l & 7;
        float col[8] = {0, 0, 0, 0, 0, 0, 0, 0};
        float rowv[8];
#pragma unroll
        for (int r = 0; r < 8; ++r) {
            const uint4 d = *reinterpret_cast<const uint4*>(
                &gxp[i * CSTR + (ys * 8 + r) * 32 + xb * 4]);
            float f0 = blo(d.x), f1 = bhi(d.x), f2 = blo(d.y), f3 = bhi(d.y);
            float f4 = blo(d.z), f5 = bhi(d.z), f6 = blo(d.w), f7 = bhi(d.w);
            rowv[r] = ((f0 + f1) + (f2 + f3)) + ((f4 + f5) + (f6 + f7));
            col[0] += f0; col[1] += f1; col[2] += f2; col[3] += f3;
            col[4] += f4; col[5] += f5; col[6] += f6; col[7] += f7;
        }
#pragma unroll
        for (int r = 0; r < 8; ++r) {
            float v = rowv[r];
            v += __shfl_xor(v, 1); v += __shfl_xor(v, 2); v += __shfl_xor(v, 4);
            if (xb == 0) Rs[i * 64 + ys * 8 + r] = v;
        }
        float tot = 0.f;
#pragma unroll
        for (int j = 0; j < 8; ++j) {
            float c = col[j];
            c += __shfl_xor(c, 8); c += __shfl_xor(c, 16); c += __shfl_xor(c, 32);
            if (ys == 0) Cs[i * 64 + xb * 8 + j] = c;
            tot += c;
        }
        tot += __shfl_xor(tot, 1); tot += __shfl_xor(tot, 2); tot += __shfl_xor(tot, 4);
        if (l == 0) Ti[i] = tot;
    }
    __syncthreads();

    // ---------------- Phase 3: gate matmul (8x8) + sigmoid ------------------
    {
        const int o = t >> 6, p = t & 63;
        float vy = b1[o], vx = b1[o];
#pragma unroll
        for (int i = 0; i < 8; ++i) {
            float wv = w1[o * 8 + i] * (1.0f / 64.0f);
            vy += wv * Rs[i * 64 + p];
            vx += wv * Cs[i * 64 + p];
        }
        sg[o * 128 + p] = sigm(vy);
        sg[o * 128 + 64 + p] = sigm(vx);
    }
    __syncthreads();

    // ---------------- Phase 4: instance-norm stats (wave i = channel i) -----
    {
        const int i = t >> 6, l = t & 63, ys = l >> 3, xb = l & 7;
        const float4 sa = *reinterpret_cast<const float4*>(&sg[i * 128 + 64 + xb * 8]);
        const float4 sb = *reinterpret_cast<const float4*>(&sg[i * 128 + 64 + xb * 8 + 4]);
        float s = 0.f, s2 = 0.f;
#pragma unroll
        for (int r = 0; r < 8; ++r) {
            const float shv = sg[i * 128 + ys * 8 + r];
            const uint4 d = *reinterpret_cast<const uint4*>(
                &gxp[i * CSTR + (ys * 8 + r) * 32 + xb * 4]);
            float g0 = blo(d.x) * shv * sa.x; s += g0; s2 += g0 * g0;
            float g1 = bhi(d.x) * shv * sa.y; s += g1; s2 += g1 * g1;
            float g2 = blo(d.y) * shv * sa.z; s += g2; s2 += g2 * g2;
            float g3 = bhi(d.y) * shv * sa.w; s += g3; s2 += g3 * g3;
            float g4 = blo(d.z) * shv * sb.x; s += g4; s2 += g4 * g4;
            float g5 = bhi(d.z) * shv * sb.y; s += g5; s2 += g5 * g5;
            float g6 = blo(d.w) * shv * sb.z; s += g6; s2 += g6 * g6;
            float g7 = bhi(d.w) * shv * sb.w; s += g7; s2 += g7 * g7;
        }
#pragma unroll
        for (int off = 32; off; off >>= 1) {
            s += __shfl_xor(s, off);
            s2 += __shfl_xor(s2, off);
        }
        if (l == 0) {
            float mu = s * (1.0f / 4096.0f);
            float var = s2 * (1.0f / 4096.0f) - mu * mu;
            float a = rsqrtf(var + 1e-5f) * gn_w[i];
            Ai[i] = a;
            Ci[i] = gn_b[i] - mu * a;
        }
    }
    // ---- Phase 5a: conv channel means from rectangle sums (wave 0) ---------
    if (t < 64) {
        const int o = t >> 3, i = t & 7;
        const float T = Ti[i];
        float part = 0.f;
#pragma unroll
        for (int ky = 0; ky < 3; ++ky) {
            int dy = ky - 1;
#pragma unroll
            for (int kx = 0; kx < 3; ++kx) {
                int dx = kx - 1;
                float S = T;
                int er = (dy < 0) ? 63 : 0;
                int ec = (dx < 0) ? 63 : 0;
                if (dy != 0) S -= Rs[i * 64 + er];
                if (dx != 0) S -= Cs[i * 64 + ec];
                if (dy != 0 && dx != 0) {
                    uint u = gxp[i * CSTR + er * 32 + (ec >> 1)];
                    S += (ec & 1) ? bhi(u) : blo(u);
                }
                part += w3[((o * 8 + i) * 3 + ky) * 3 + kx] * S;
            }
        }
        part += __shfl_xor(part, 1); part += __shfl_xor(part, 2); part += __shfl_xor(part, 4);
        if (i == 0) m2s[o] = part * (1.0f / 4096.0f) + b3[o];
    }
    // ---- Phase 5b: the two 8-way softmaxes (same wave as 5a writers) -------
    if (t < 8) {
        float mx = m2s[0];
#pragma unroll
        for (int o = 1; o < 8; ++o) mx = fmaxf(mx, m2s[o]);
        float sum = 0.f;
#pragma unroll
        for (int o = 0; o < 8; ++o) sum += __expf(m2s[o] - mx);
        x21s[t] = __expf(m2s[t] - mx) / sum;
        // x1 spatial mean == gn_b exactly (normalized field)
        float mx1 = gn_b[0];
#pragma unroll
        for (int o = 1; o < 8; ++o) mx1 = fmaxf(mx1, gn_b[o]);
        float sum1 = 0.f;
#pragma unroll
        for (int o = 0; o < 8; ++o) sum1 += __expf(gn_b[o] - mx1);
        x11s[t] = __expf(gn_b[t] - mx1) / sum1;
    }
    __syncthreads();

    // ---- Phase 5c: collapsed filter (padded [8][12]), t1, constants --------
    if (t < 72) {
        const int i = t / 9, k = t % 9;
        float acc = 0.f;
#pragma unroll
        for (int o = 0; o < 8; ++o) acc += x11s[o] * w3[(o * 8 + i) * 9 + k];
        weff[i * 12 + (k / 3) * 4 + (k % 3)] = acc;
    }
    {
        const int i = t >> 6, y = t & 63;
        t1s[i * 64 + y] = x21s[i] * Ai[i] * sg[i * 128 + y];
    }
    if (t == 0) {
        float wc = 0.f;
#pragma unroll
        for (int o = 0; o < 8; ++o) wc += x11s[o] * b3[o] + x21s[o] * Ci[o];
        wconst_s = wc;
    }
    __syncthreads();

    // ---- Phase 6: per-pixel weight, sigmoid, output (fused) ----------------
    {
        const int y = t >> 3, xb = t & 7;      // 8 consecutive px per thread
        float ws0 = wconst_s, ws1 = wconst_s, ws2 = wconst_s, ws3 = wconst_s;
        float ws4 = wconst_s, ws5 = wconst_s, ws6 = wconst_s, ws7 = wconst_s;
        uint4 gla[8];
#pragma unroll
        for (int i = 0; i < 8; ++i) {
            const float t1v = t1s[i * 64 + y];
            const float4 sa = *reinterpret_cast<const float4*>(&sg[i * 128 + 64 + xb * 8]);
            const float4 sb = *reinterpret_cast<const float4*>(&sg[i * 128 + 64 + xb * 8 + 4]);
#pragma unroll
            for (int dy = -1; dy <= 1; ++dy) {
                const int yy = y + dy;
                if (yy < 0 || yy > 63) continue;   // diverges only in first/last y-octet
                const uint4 d = *reinterpret_cast<const uint4*>(
                    &gxp[i * CSTR + yy * 32 + xb * 4]);
                float f0 = blo(d.x), f1 = bhi(d.x), f2 = blo(d.y), f3 = bhi(d.y);
                float f4 = blo(d.z), f5 = bhi(d.z), f6 = blo(d.w), f7 = bhi(d.w);
                float vm = __shfl_up(f7, 1);       // prev lane's last px (same row)
                float vp = __shfl_down(f0, 1);     // next lane's first px
                vm = (xb == 0) ? 0.f : vm;
                vp = (xb == 7) ? 0.f : vp;
                const float4 wv = *reinterpret_cast<const float4*>(&weff[i * 12 + (dy + 1) * 4]);
                const float wl = wv.x, wc = wv.y, wr = wv.z;
                ws0 += wl * vm + wc * f0 + wr * f1;
                ws1 += wl * f0 + wc * f1 + wr * f2;
                ws2 += wl * f1 + wc * f2 + wr * f3;
                ws3 += wl * f2 + wc * f3 + wr * f4;
                ws4 += wl * f3 + wc * f4 + wr * f5;
                ws5 += wl * f4 + wc * f5 + wr * f6;
                ws6 += wl * f5 + wc * f6 + wr * f7;
                ws7 += wl * f6 + wc * f7 + wr * vp;
                if (dy == 0) {
                    gla[i] = d;
                    ws0 += t1v * sa.x * f0;  ws1 += t1v * sa.y * f1;
                    ws2 += t1v * sa.z * f2;  ws3 += t1v * sa.w * f3;
                    ws4 += t1v * sb.x * f4;  ws5 += t1v * sb.y * f5;
                    ws6 += t1v * sb.z * f6;  ws7 += t1v * sb.w * f7;
                }
            }
        }
        const float s0 = sigm(ws0), s1 = sigm(ws1), s2 = sigm(ws2), s3 = sigm(ws3);
        const float s4 = sigm(ws4), s5 = sigm(ws5), s6 = sigm(ws6), s7 = sigm(ws7);
        float4* out4 = reinterpret_cast<float4*>(out) + (size_t)b * 4096 * 64 + g * 2;
        const size_t pb = (size_t)(y * 64 + xb * 8) * 64;
        float4 lo, hi;
        lo.x = blo(gla[0].x) * s0; lo.y = blo(gla[1].x) * s0; lo.z = blo(gla[2].x) * s0; lo.w = blo(gla[3].x) * s0;
        hi.x = blo(gla[4].x) * s0; hi.y = blo(gla[5].x) * s0; hi.z = blo(gla[6].x) * s0; hi.w = blo(gla[7].x) * s0;
        out4[pb + 0] = lo; out4[pb + 1] = hi;
        lo.x = bhi(gla[0].x) * s1; lo.y = bhi(gla[1].x) * s1; lo.z = bhi(gla[2].x) * s1; lo.w = bhi(gla[3].x) * s1;
        hi.x = bhi(gla[4].x) * s1; hi.y = bhi(gla[5].x) * s1; hi.z = bhi(gla[6].x) * s1; hi.w = bhi(gla[7].x) * s1;
        out4[pb + 64] = lo; out4[pb + 65] = hi;
        lo.x = blo(gla[0].y) * s2; lo.y = blo(gla[1].y) * s2; lo.z = blo(gla[2].y) * s2; lo.w = blo(gla[3].y) * s2;
        hi.x = blo(gla[4].y) * s2; hi.y = blo(gla[5].y) * s2; hi.z = blo(gla[6].y) * s2; hi.w = blo(gla[7].y) * s2;
        out4[pb + 128] = lo; out4[pb + 129] = hi;
        lo.x = bhi(gla[0].y) * s3; lo.y = bhi(gla[1].y) * s3; lo.z = bhi(gla[2].y) * s3; lo.w = bhi(gla[3].y) * s3;
        hi.x = bhi(gla[4].y) * s3; hi.y = bhi(gla[5].y) * s3; hi.z = bhi(gla[6].y) * s3; hi.w = bhi(gla[7].y) * s3;
        out4[pb + 192] = lo; out4[pb + 193] = hi;
        lo.x = blo(gla[0].z) * s4; lo.y = blo(gla[1].z) * s4; lo.z = blo(gla[2].z) * s4; lo.w = blo(gla[3].z) * s4;
        hi.x = blo(gla[4].z) * s4; hi.y = blo(gla[5].z) * s4; hi.z = blo(gla[6].z) * s4; hi.w = blo(gla[7].z) * s4;
        out4[pb + 256] = lo; out4[pb + 257] = hi;
        lo.x = bhi(gla[0].z) * s5; lo.y = bhi(gla[1].z) * s5; lo.z = bhi(gla[2].z) * s5; lo.w = bhi(gla[3].z) * s5;
        hi.x = bhi(gla[4].z) * s5; hi.y = bhi(gla[5].z) * s5; hi.z = bhi(gla[6].z) * s5; hi.w = bhi(gla[7].z) * s5;
        out4[pb + 320] = lo; out4[pb + 321] = hi;
        lo.x = blo(gla[0].w) * s6; lo.y = blo(gla[1].w) * s6; lo.z = blo(gla[2].w) * s6; lo.w = blo(gla[3].w) * s6;
        hi.x = blo(gla[4].w) * s6; hi.y = blo(gla[5].w) * s6; hi.z = blo(gla[6].w) * s6; hi.w = blo(gla[7].w) * s6;
        out4[pb + 384] = lo; out4[pb + 385] = hi;
        lo.x = bhi(gla[0].w) * s7; lo.y = bhi(gla[1].w) * s7; lo.z = bhi(gla[2].w) * s7; lo.w = bhi(gla[3].w) * s7;
        hi.x = bhi(gla[4].w) * s7; hi.y = bhi(gla[5].w) * s7; hi.z = bhi(gla[6].w) * s7; hi.w = bhi(gla[7].w) * s7;
        out4[pb + 448] = lo; out4[pb + 449] = hi;
    }
}

extern "C" void kernel_launch(void* const* d_in, const int* in_sizes, int n_in,
                              void* d_out, int out_size, void* d_ws, size_t ws_size,
                              hipStream_t stream) {
    const float* x    = (const float*)d_in[0];
    const float* w1   = (const float*)d_in[1];
    const float* b1   = (const float*)d_in[2];
    const float* w3   = (const float*)d_in[3];
    const float* b3   = (const float*)d_in[4];
    const float* gn_w = (const float*)d_in[5];
    const float* gn_b = (const float*)d_in[6];
    float* out = (float*)d_out;

    hipLaunchKernelGGL(fused_ema_kernel, dim3(NBLK), dim3(NTHR), 0, stream,
                       x, w1, b1, w3, b3, gn_w, gn_b, out);
}